// Round 10
// baseline (5210.064 us; speedup 1.0000x reference)
//
#include <hip/hip_runtime.h>
#include <hip/hip_bf16.h>

// GaussianLSTM: x(4,512,256) -> 2-layer LSTM(H=256) -> Gaussian head.
// Outputs concat: sample (524288) | mu (524288) | std_full (134217728) f32.
//
// Round 10: r9 pipeline + two targeted fixes.
//   FIX 1 (registers): __launch_bounds__ 2nd arg was ignored (r8->r9 bit-
//     identical, VGPR_Count=128, weight set spilled). Pin the allocator with
//     the native attribute amdgpu_waves_per_eu(2,2) -> 256 VGPR/wave.
//   FIX 2 (write amplification + poll latency): pubX1 was strided m*256 ->
//     each store instr touched ~16 64B lines with 8B each (and each poll
//     round re-read them). New layout: consumer lane (w,b,G) == producer
//     lane (w,b,G), so each lane's 16 tagged words live in ONE contiguous
//     128B block: [t][phase][wave][slot=b*4+G][16 words].
//   Structure unchanged: 3 CUs; 8 waves x (6 reg tiles + 2 LDS tiles);
//   WG0 (L0) -> tagged h0 -> WG1 (xw1 = bias1 + W_ih1 @ h0) -> tagged xw1
//   -> WG2 (L1) -> hs1. Tags share the u64 with payload (no fences/acks).
//   Replay-safe: pubs in std_full region, rewritten by finalize each call.

#define HD 256
#define SEQ 512

typedef __attribute__((ext_vector_type(8))) short short8;
typedef __attribute__((ext_vector_type(4))) float f32x4;
using u16 = unsigned short;
using u32 = unsigned int;
using u64 = unsigned long long;

#define MFMA16(a, bm, c) __builtin_amdgcn_mfma_f32_16x16x32_bf16((a), (bm), (c), 0, 0, 0)

__device__ inline u16 f2bf(float x) {
  u32 u = __float_as_uint(x);
  u32 r = (u + 0x7FFFu + ((u >> 16) & 1u)) >> 16;
  return (u16)r;
}
__device__ inline u32 pk2(float a, float b) {
  return (u32)f2bf(a) | ((u32)f2bf(b) << 16);
}
__device__ inline float fast_sigmoid(float z) { return 1.0f / (1.0f + __expf(-z)); }
__device__ inline float fast_tanh(float z) { return 1.0f - 2.0f / (1.0f + __expf(2.0f * z)); }

__device__ __forceinline__ u64 aload(const u64* p) {
  return __hip_atomic_load(p, __ATOMIC_RELAXED, __HIP_MEMORY_SCOPE_AGENT);
}
__device__ __forceinline__ void astore(u64* p, u64 v) {
  __hip_atomic_store(p, v, __ATOMIC_RELAXED, __HIP_MEMORY_SCOPE_AGENT);
}

__device__ __forceinline__ f32x4 unpack4(uint2 p) {
  return f32x4{__uint_as_float(p.x << 16), __uint_as_float(p.x & 0xFFFF0000u),
               __uint_as_float(p.y << 16), __uint_as_float(p.y & 0xFFFF0000u)};
}

__device__ __forceinline__ void epi_h(const f32x4 (&acc)[4], f32x4& cq, f32x4& h) {
#pragma unroll
  for (int r = 0; r < 4; ++r) {
    const float gi = fast_sigmoid(acc[0][r]);
    const float gf = fast_sigmoid(acc[1][r]);
    const float gg = fast_tanh(acc[2][r]);
    const float go = fast_sigmoid(acc[3][r]);
    cq[r] = gf * cq[r] + gi * gg;
    h[r] = go * fast_tanh(cq[r]);
  }
}

// ---------------- prep: pack W_hh0/W_ih1/W_hh1 into bf16 MFMA-frag layout ----
// pk[mat][ti][kk][ll][j]: ti = dg*4 + m (dg 0..15, m 0..3);
// row = m*256 + dg*16 + (ll&15); k = kk*32 + (ll>>4)*8 + j.
__global__ __launch_bounds__(256) void prep_pack2(
    const float* __restrict__ whh0, const float* __restrict__ wih1,
    const float* __restrict__ whh1, const float* __restrict__ bi1,
    const float* __restrict__ bh1, u16* __restrict__ pk,
    float* __restrict__ bias1s) {
  const int idx = blockIdx.x * 256 + threadIdx.x;
  if (idx < 786432) {
    const int mat = idx >> 18;
    const int e = idx & 262143;
    const int ti = e >> 12, r2 = e & 4095;
    const int kk = r2 >> 9, ll = (r2 >> 3) & 63, j = r2 & 7;
    const int dg = ti >> 2, m = ti & 3;
    const int row = m * 256 + dg * 16 + (ll & 15);
    const int k = kk * 32 + (ll >> 4) * 8 + j;
    const float* src = (mat == 0) ? whh0 : (mat == 1) ? wih1 : whh1;
    pk[idx] = f2bf(src[(size_t)row * 256 + k]);
  } else {
    const int i = idx - 786432;
    if (i < 1024) bias1s[i] = bi1[i] + bh1[i];
  }
}

// --------------------- xw0 = x @ w_ih0^T + biases, packed bf16 ----------------
__global__ __launch_bounds__(256) void xw_gemm_bf(
    const float* __restrict__ xin, const float* __restrict__ w,
    const float* __restrict__ ba, const float* __restrict__ bb,
    u16* __restrict__ xwp) {
  __shared__ float xs[4][HD];
  const int blk = blockIdx.x, tid = threadIdx.x;
  const int row0 = blk * 4;
  for (int i = tid; i < 4 * HD; i += 256) xs[i >> 8][i & 255] = xin[(size_t)row0 * HD + i];
  __syncthreads();
  float acc[4][4];
#pragma unroll
  for (int g = 0; g < 4; ++g)
#pragma unroll
    for (int tt = 0; tt < 4; ++tt) acc[g][tt] = 0.f;
#pragma unroll 2
  for (int kc = 0; kc < 64; ++kc) {
#pragma unroll
    for (int g = 0; g < 4; ++g) {
      const int r = g * HD + tid;
      const float4 wv = ((const float4*)(w + (size_t)r * HD))[kc];
#pragma unroll
      for (int tt = 0; tt < 4; ++tt) {
        const float4 hv = ((const float4*)xs[tt])[kc];
        acc[g][tt] += wv.x * hv.x + wv.y * hv.y + wv.z * hv.z + wv.w * hv.w;
      }
    }
  }
#pragma unroll
  for (int g = 0; g < 4; ++g) {
    const int r = g * HD + tid;
    const float bias = ba[r] + bb[r];
#pragma unroll
    for (int tt = 0; tt < 4; ++tt)
      xwp[(size_t)(row0 + tt) * 1024 + r] = f2bf(acc[g][tt] + bias);
  }
}

// ------------------------------------------------------------- 3-CU LSTM
__global__ __launch_bounds__(512)
__attribute__((amdgpu_waves_per_eu(2, 2))) void lstm8w(
    const u16* __restrict__ xwp, const u16* __restrict__ pk,
    const float* __restrict__ bias1s, float* __restrict__ hs1,
    u64* __restrict__ pubH0, u64* __restrict__ pubX1) {
  __shared__ __align__(16) u16 ldsW[16][4096];   // 128 KB: 16 weight tiles
  __shared__ __align__(16) u16 hbuf[2][4][264];  // h bf16, ping-pong

  const int role = blockIdx.x;  // 0: L0, 1: streamer, 2: L1
  const int tid = threadIdx.x;
  const int w = tid >> 6, l = tid & 63;
  const int r16 = l & 15, G = l >> 4;
  const bool active = (r16 < 4);
  const int b = r16;
  const int beff = active ? b : 3;
  const int dgA = 2 * w, dgB = 2 * w + 1;
  const u16* pkm = pk + (size_t)role * 262144;
  // lane-contiguous xw1 block base: [t][ph][w][slot=b*4+G][16 words]
  const size_t xslot = ((size_t)w * 16 + (b * 4 + G)) * 16;

  for (int i = tid; i < 2112; i += 512) ((u16*)hbuf)[i] = 0;
  // LDS tiles: slot s -> wave s>>1, dg = 2*(s>>1)+1, m = 2+(s&1)
  for (int u = tid; u < 8192; u += 512) {
    const int s = u >> 9, inner = u & 511;
    const int ti = (2 * (s >> 1) + 1) * 4 + 2 + (s & 1);
    *(short8*)&ldsW[s][inner * 8] = *(const short8*)(pkm + (size_t)ti * 4096 + inner * 8);
  }
  // register tiles: dgA gates 0..3, dgB gates 0..1  (192 VGPR)
  short8 wf[6][8];
#pragma unroll
  for (int i = 0; i < 4; ++i)
#pragma unroll
    for (int kk = 0; kk < 8; ++kk)
      wf[i][kk] = *(const short8*)(pkm + ((size_t)(dgA * 4 + i) * 8 + kk) * 512 + l * 8);
#pragma unroll
  for (int i = 0; i < 2; ++i)
#pragma unroll
    for (int kk = 0; kk < 8; ++kk)
      wf[4 + i][kk] = *(const short8*)(pkm + ((size_t)(dgB * 4 + i) * 8 + kk) * 512 + l * 8);
  const u16* lw0 = &ldsW[2 * w][0];
  const u16* lw1 = &ldsW[2 * w + 1][0];
  __syncthreads();

  if (role == 0) {
    // ------------- layer 0 -------------
    f32x4 cA = {0.f, 0.f, 0.f, 0.f}, cB = cA;
    uint2 xnA[4], xnB[4];
    if (active) {
#pragma unroll
      for (int m = 0; m < 4; ++m) {
        xnA[m] = *(const uint2*)(xwp + (size_t)b * SEQ * 1024 + m * 256 + dgA * 16 + G * 4);
        xnB[m] = *(const uint2*)(xwp + (size_t)b * SEQ * 1024 + m * 256 + dgB * 16 + G * 4);
      }
    }
    for (int t = 0; t < SEQ; ++t) {
      const int cur = t & 1, nxt = cur ^ 1;
      const u16* hr = &hbuf[cur][beff][0];
      const int tn = (t + 1 < SEQ) ? t + 1 : t;
      const u64 tg = (u64)(u32)(t + 1) << 32;
      // ---- phase A (dgA): all-register tiles
      f32x4 aA[4];
#pragma unroll
      for (int m = 0; m < 4; ++m) aA[m] = active ? unpack4(xnA[m]) : f32x4{0.f, 0.f, 0.f, 0.f};
      if (active) {
#pragma unroll
        for (int m = 0; m < 4; ++m)
          xnA[m] = *(const uint2*)(xwp + ((size_t)b * SEQ + tn) * 1024 + m * 256 + dgA * 16 + G * 4);
      }
#pragma unroll
      for (int kk = 0; kk < 8; ++kk) {
        const short8 bk = *(const short8*)(hr + kk * 32 + G * 8);
        aA[0] = MFMA16(wf[0][kk], bk, aA[0]);
        aA[1] = MFMA16(wf[1][kk], bk, aA[1]);
        aA[2] = MFMA16(wf[2][kk], bk, aA[2]);
        aA[3] = MFMA16(wf[3][kk], bk, aA[3]);
      }
      if (active) {
        f32x4 h;
        epi_h(aA, cA, h);
        const u32 lo = pk2(h[0], h[1]), hi = pk2(h[2], h[3]);
        *(u32*)&hbuf[nxt][b][dgA * 16 + G * 4] = lo;
        *(u32*)&hbuf[nxt][b][dgA * 16 + G * 4 + 2] = hi;
        const size_t wi = (size_t)t * 512 + b * 128 + dgA * 8 + G * 2;
        astore(pubH0 + wi, (u64)lo | tg);
        astore(pubH0 + wi + 1, (u64)hi | tg);
      }
      // ---- phase B (dgB): 2 reg + 2 LDS tiles
      f32x4 aB[4];
#pragma unroll
      for (int m = 0; m < 4; ++m) aB[m] = active ? unpack4(xnB[m]) : f32x4{0.f, 0.f, 0.f, 0.f};
      if (active) {
#pragma unroll
        for (int m = 0; m < 4; ++m)
          xnB[m] = *(const uint2*)(xwp + ((size_t)b * SEQ + tn) * 1024 + m * 256 + dgB * 16 + G * 4);
      }
#pragma unroll
      for (int kk = 0; kk < 8; ++kk) {
        const short8 bk = *(const short8*)(hr + kk * 32 + G * 8);
        aB[0] = MFMA16(wf[4][kk], bk, aB[0]);
        aB[1] = MFMA16(wf[5][kk], bk, aB[1]);
        aB[2] = MFMA16(*(const short8*)(lw0 + kk * 512 + l * 8), bk, aB[2]);
        aB[3] = MFMA16(*(const short8*)(lw1 + kk * 512 + l * 8), bk, aB[3]);
      }
      if (active) {
        f32x4 h;
        epi_h(aB, cB, h);
        const u32 lo = pk2(h[0], h[1]), hi = pk2(h[2], h[3]);
        *(u32*)&hbuf[nxt][b][dgB * 16 + G * 4] = lo;
        *(u32*)&hbuf[nxt][b][dgB * 16 + G * 4 + 2] = hi;
        const size_t wi = (size_t)t * 512 + b * 128 + dgB * 8 + G * 2;
        astore(pubH0 + wi, (u64)lo | tg);
        astore(pubH0 + wi + 1, (u64)hi | tg);
      }
      __syncthreads();
    }
  } else if (role == 1) {
    // ------------- xw1 streamer -------------
    for (int t = 0; t < SEQ; ++t) {
      const int cur = t & 1;
      {  // stage h0(t): 1 tagged word per thread
        const u64* bp = pubH0 + (size_t)t * 512 + tid;
        u64 v = aload(bp);
        while ((u32)(v >> 32) != (u32)(t + 1)) v = aload(bp);
        *(u32*)&hbuf[cur][tid >> 7][(tid & 127) * 2] = (u32)v;
      }
      __syncthreads();
      const u16* hr = &hbuf[cur][beff][0];
      const u64 tg = (u64)(u32)(t + 1) << 32;
      // ---- phase A
      f32x4 aA[4];
#pragma unroll
      for (int m = 0; m < 4; ++m)
        aA[m] = active ? *(const f32x4*)(bias1s + m * 256 + dgA * 16 + G * 4)
                       : f32x4{0.f, 0.f, 0.f, 0.f};
#pragma unroll
      for (int kk = 0; kk < 8; ++kk) {
        const short8 bk = *(const short8*)(hr + kk * 32 + G * 8);
        aA[0] = MFMA16(wf[0][kk], bk, aA[0]);
        aA[1] = MFMA16(wf[1][kk], bk, aA[1]);
        aA[2] = MFMA16(wf[2][kk], bk, aA[2]);
        aA[3] = MFMA16(wf[3][kk], bk, aA[3]);
      }
      if (active) {
        u64* xb = pubX1 + ((size_t)t * 2 + 0) * 2048 + xslot;
#pragma unroll
        for (int m = 0; m < 4; ++m)
#pragma unroll
          for (int r = 0; r < 4; ++r)
            astore(xb + m * 4 + r, (u64)__float_as_uint(aA[m][r]) | tg);
      }
      // ---- phase B
      f32x4 aB[4];
#pragma unroll
      for (int m = 0; m < 4; ++m)
        aB[m] = active ? *(const f32x4*)(bias1s + m * 256 + dgB * 16 + G * 4)
                       : f32x4{0.f, 0.f, 0.f, 0.f};
#pragma unroll
      for (int kk = 0; kk < 8; ++kk) {
        const short8 bk = *(const short8*)(hr + kk * 32 + G * 8);
        aB[0] = MFMA16(wf[4][kk], bk, aB[0]);
        aB[1] = MFMA16(wf[5][kk], bk, aB[1]);
        aB[2] = MFMA16(*(const short8*)(lw0 + kk * 512 + l * 8), bk, aB[2]);
        aB[3] = MFMA16(*(const short8*)(lw1 + kk * 512 + l * 8), bk, aB[3]);
      }
      if (active) {
        u64* xb = pubX1 + ((size_t)t * 2 + 1) * 2048 + xslot;
#pragma unroll
        for (int m = 0; m < 4; ++m)
#pragma unroll
          for (int r = 0; r < 4; ++r)
            astore(xb + m * 4 + r, (u64)__float_as_uint(aB[m][r]) | tg);
      }
    }
  } else {
    // ------------- layer 1 -------------
    f32x4 cA = {0.f, 0.f, 0.f, 0.f}, cB = cA;
    for (int t = 0; t < SEQ; ++t) {
      const int cur = t & 1, nxt = cur ^ 1;
      const u16* hr = &hbuf[cur][beff][0];
      // ---- phase A: poll xw1(dgA) — 16 contiguous tagged words (2 lines)
      f32x4 aA[4];
      if (active) {
        const u64* xb = pubX1 + ((size_t)t * 2 + 0) * 2048 + xslot;
        u64 v[16];
        for (;;) {
#pragma unroll
          for (int s = 0; s < 16; ++s) v[s] = aload(xb + s);
          bool ok = true;
#pragma unroll
          for (int s = 0; s < 16; ++s) ok = ok && ((u32)(v[s] >> 32) == (u32)(t + 1));
          if (__all(ok)) break;
        }
#pragma unroll
        for (int m = 0; m < 4; ++m)
          aA[m] = f32x4{__uint_as_float((u32)v[m * 4 + 0]), __uint_as_float((u32)v[m * 4 + 1]),
                        __uint_as_float((u32)v[m * 4 + 2]), __uint_as_float((u32)v[m * 4 + 3])};
      } else {
#pragma unroll
        for (int m = 0; m < 4; ++m) aA[m] = f32x4{0.f, 0.f, 0.f, 0.f};
      }
#pragma unroll
      for (int kk = 0; kk < 8; ++kk) {
        const short8 bk = *(const short8*)(hr + kk * 32 + G * 8);
        aA[0] = MFMA16(wf[0][kk], bk, aA[0]);
        aA[1] = MFMA16(wf[1][kk], bk, aA[1]);
        aA[2] = MFMA16(wf[2][kk], bk, aA[2]);
        aA[3] = MFMA16(wf[3][kk], bk, aA[3]);
      }
      if (active) {
        f32x4 h;
        epi_h(aA, cA, h);
        *(u32*)&hbuf[nxt][b][dgA * 16 + G * 4] = pk2(h[0], h[1]);
        *(u32*)&hbuf[nxt][b][dgA * 16 + G * 4 + 2] = pk2(h[2], h[3]);
        *(f32x4*)(hs1 + ((size_t)b * SEQ + t) * HD + dgA * 16 + G * 4) = h;
      }
      // ---- phase B
      f32x4 aB[4];
      if (active) {
        const u64* xb = pubX1 + ((size_t)t * 2 + 1) * 2048 + xslot;
        u64 v[16];
        for (;;) {
#pragma unroll
          for (int s = 0; s < 16; ++s) v[s] = aload(xb + s);
          bool ok = true;
#pragma unroll
          for (int s = 0; s < 16; ++s) ok = ok && ((u32)(v[s] >> 32) == (u32)(t + 1));
          if (__all(ok)) break;
        }
#pragma unroll
        for (int m = 0; m < 4; ++m)
          aB[m] = f32x4{__uint_as_float((u32)v[m * 4 + 0]), __uint_as_float((u32)v[m * 4 + 1]),
                        __uint_as_float((u32)v[m * 4 + 2]), __uint_as_float((u32)v[m * 4 + 3])};
      } else {
#pragma unroll
        for (int m = 0; m < 4; ++m) aB[m] = f32x4{0.f, 0.f, 0.f, 0.f};
      }
#pragma unroll
      for (int kk = 0; kk < 8; ++kk) {
        const short8 bk = *(const short8*)(hr + kk * 32 + G * 8);
        aB[0] = MFMA16(wf[4][kk], bk, aB[0]);
        aB[1] = MFMA16(wf[5][kk], bk, aB[1]);
        aB[2] = MFMA16(*(const short8*)(lw0 + kk * 512 + l * 8), bk, aB[2]);
        aB[3] = MFMA16(*(const short8*)(lw1 + kk * 512 + l * 8), bk, aB[3]);
      }
      if (active) {
        f32x4 h;
        epi_h(aB, cB, h);
        *(u32*)&hbuf[nxt][b][dgB * 16 + G * 4] = pk2(h[0], h[1]);
        *(u32*)&hbuf[nxt][b][dgB * 16 + G * 4 + 2] = pk2(h[2], h[3]);
        *(f32x4*)(hs1 + ((size_t)b * SEQ + t) * HD + dgB * 16 + G * 4) = h;
      }
      __syncthreads();
    }
  }
}

// ------------------------------------------------- head: stats = h @ w_lin^T + b
__global__ __launch_bounds__(256) void head_stats(
    const float* __restrict__ hs1, const float* __restrict__ wlin,
    const float* __restrict__ blin, float* __restrict__ mu_out,
    float* __restrict__ sd_out) {
  __shared__ float hsm[4][HD];
  const int blk = blockIdx.x, tid = threadIdx.x;
  const int row0 = blk * 4;
  for (int i = tid; i < 4 * HD; i += 256) hsm[i >> 8][i & 255] = hs1[(size_t)row0 * HD + i];
  __syncthreads();
  const float4* wsd = (const float4*)(wlin + (size_t)tid * HD);
  const float4* wmu = (const float4*)(wlin + (size_t)(HD + tid) * HD);
  float asd[4] = {0, 0, 0, 0}, amu[4] = {0, 0, 0, 0};
#pragma unroll 4
  for (int kc = 0; kc < 64; ++kc) {
    const float4 ws = wsd[kc], wm = wmu[kc];
#pragma unroll
    for (int tt = 0; tt < 4; ++tt) {
      const float4 hv = ((const float4*)hsm[tt])[kc];
      asd[tt] += ws.x * hv.x + ws.y * hv.y + ws.z * hv.z + ws.w * hv.w;
      amu[tt] += wm.x * hv.x + wm.y * hv.y + wm.z * hv.z + wm.w * hv.w;
    }
  }
  const float bsd = blin[tid], bmu = blin[HD + tid];
#pragma unroll
  for (int tt = 0; tt < 4; ++tt) {
    const float zs = asd[tt] + bsd;
    const float sp = (zs > 15.f) ? zs : __logf(1.f + __expf(zs));  // softplus
    sd_out[(size_t)(row0 + tt) * HD + tid] = sp;
    mu_out[(size_t)(row0 + tt) * HD + tid] = amu[tt] + bmu;
  }
}

// ---------------------------------- finalize: std_full + sample
__global__ __launch_bounds__(256) void finalize_fill(
    const float* __restrict__ eps, float* __restrict__ out) {
  float* sample = out;        // currently holds softplus(std) temp
  float* mu = out + 524288;
  float* sf = out + 1048576;  // [2048][256][256]
  const int row = blockIdx.x;
  const int tid = threadIdx.x;
  __shared__ float sd[HD];
  sd[tid] = sample[(size_t)row * HD + tid];
  __syncthreads();
  float4* dst = (float4*)(sf + (size_t)row * HD * HD);
  const int rr = tid >> 6, m = tid & 63;
#pragma unroll 4
  for (int g = 0; g < 64; ++g) {
    const int r = g * 4 + rr;
    float4 v = make_float4(0.f, 0.f, 0.f, 0.f);
    const int base = m * 4;
    if (r >= base && r < base + 4) ((float*)&v)[r - base] = sd[r];
    dst[(size_t)r * 64 + m] = v;
  }
  const float mu_v = mu[(size_t)row * HD + tid];
  const float e = eps[(size_t)row * HD + tid];
  sample[(size_t)row * HD + tid] = mu_v + sqrtf(sd[tid]) * e;
}

extern "C" void kernel_launch(void* const* d_in, const int* in_sizes, int n_in,
                              void* d_out, int out_size, void* d_ws, size_t ws_size,
                              hipStream_t stream) {
  const float* x     = (const float*)d_in[0];
  const float* eps   = (const float*)d_in[1];
  const float* w_ih0 = (const float*)d_in[2];
  const float* w_hh0 = (const float*)d_in[3];
  const float* b_ih0 = (const float*)d_in[4];
  const float* b_hh0 = (const float*)d_in[5];
  const float* w_ih1 = (const float*)d_in[6];
  const float* w_hh1 = (const float*)d_in[7];
  const float* b_ih1 = (const float*)d_in[8];
  const float* b_hh1 = (const float*)d_in[9];
  const float* w_lin = (const float*)d_in[10];
  const float* b_lin = (const float*)d_in[11];
  float* out = (float*)d_out;

  // Scratch carved from std_full output region (fully rewritten by finalize
  // each call -> tags never stale at launch; replay-safe).
  float* scratch = out + 1048576;
  u16*   xwp    = (u16*)scratch;                // 2,097,152 u16 (4 MB)
  float* hs1    = scratch + 1048576;            //   524,288 f32
  u16*   pkW    = (u16*)(scratch + 1572864);    //   786,432 u16
  float* bias1s = scratch + 1966080;            //     1,024 f32
  u64*   pubH0  = (u64*)(scratch + 1967104);    //   262,144 u64 (2 MB)
  u64*   pubX1  = (u64*)(scratch + 2491392);    // 2,097,152 u64 (16 MB)

  hipLaunchKernelGGL(prep_pack2, dim3(3076), dim3(256), 0, stream,
                     w_hh0, w_ih1, w_hh1, b_ih1, b_hh1, pkW, bias1s);
  hipLaunchKernelGGL(xw_gemm_bf, dim3(512), dim3(256), 0, stream,
                     x, w_ih0, b_ih0, b_hh0, xwp);
  hipLaunchKernelGGL(lstm8w, dim3(3), dim3(512), 0, stream,
                     xwp, pkW, bias1s, hs1, pubH0, pubX1);
  hipLaunchKernelGGL(head_stats, dim3(512), dim3(256), 0, stream, hs1, w_lin, b_lin,
                     out + 524288, out);
  hipLaunchKernelGGL(finalize_fill, dim3(2048), dim3(256), 0, stream, eps, out);
}

// Round 11
// 2480.685 us; speedup vs baseline: 2.1003x; 2.1003x over previous
//
#include <hip/hip_runtime.h>
#include <hip/hip_bf16.h>

// GaussianLSTM: x(4,512,256) -> 2-layer LSTM(H=256) -> Gaussian head.
// Outputs concat: sample (524288) | mu (524288) | std_full (134217728) f32.
//
// Round 11: 4-CU-per-GEMV, all-LDS weights (spill-proof at any VGPR grant).
//   hipcc pins 512-thr blocks at 128 VGPR (r8/r9/r10: all attributes
//   ignored) -> stop fighting the allocator. Each matrix is split over 4
//   CUs (64 dims x 4 gates = 16 tiles = 128 KB LDS each); waves need only
//   ~80 live VGPRs. Recurrence = 4-CU lockstep via tagged u64 words
//   ({payload|tag} in one word: no fences/acks/tokens; parallel polls ->
//   ~1 L2 latency per step).
//   Roles (blockIdx/4): 0 = L0 (consumes xw0, publishes h0),
//   1 = streamer (xw1 = bias1 + W_ih1 @ h0, publishes tagged f32 words),
//   2 = L1 (consumes xw1, publishes h1, writes hs1). 12 WGs x 256 thr.
//   Replay-safe: pubs live in std_full scratch; finalize_fill rewrites the
//   whole region each call (f32/0xAA bit patterns never equal tags 1..512).

#define HD 256
#define SEQ 512

typedef __attribute__((ext_vector_type(8))) short short8;
typedef __attribute__((ext_vector_type(4))) float f32x4;
using u16 = unsigned short;
using u32 = unsigned int;
using u64 = unsigned long long;

#define MFMA16(a, bm, c) __builtin_amdgcn_mfma_f32_16x16x32_bf16((a), (bm), (c), 0, 0, 0)

__device__ inline u16 f2bf(float x) {
  u32 u = __float_as_uint(x);
  u32 r = (u + 0x7FFFu + ((u >> 16) & 1u)) >> 16;
  return (u16)r;
}
__device__ inline u32 pk2(float a, float b) {
  return (u32)f2bf(a) | ((u32)f2bf(b) << 16);
}
__device__ inline float fast_sigmoid(float z) { return 1.0f / (1.0f + __expf(-z)); }
__device__ inline float fast_tanh(float z) { return 1.0f - 2.0f / (1.0f + __expf(2.0f * z)); }

__device__ __forceinline__ u64 aload(const u64* p) {
  return __hip_atomic_load(p, __ATOMIC_RELAXED, __HIP_MEMORY_SCOPE_AGENT);
}
__device__ __forceinline__ void astore(u64* p, u64 v) {
  __hip_atomic_store(p, v, __ATOMIC_RELAXED, __HIP_MEMORY_SCOPE_AGENT);
}

__device__ __forceinline__ f32x4 unpack4(uint2 p) {
  return f32x4{__uint_as_float(p.x << 16), __uint_as_float(p.x & 0xFFFF0000u),
               __uint_as_float(p.y << 16), __uint_as_float(p.y & 0xFFFF0000u)};
}

__device__ __forceinline__ void epi_h(const f32x4 (&acc)[4], f32x4& cq, f32x4& h) {
#pragma unroll
  for (int r = 0; r < 4; ++r) {
    const float gi = fast_sigmoid(acc[0][r]);
    const float gf = fast_sigmoid(acc[1][r]);
    const float gg = fast_tanh(acc[2][r]);
    const float go = fast_sigmoid(acc[3][r]);
    cq[r] = gf * cq[r] + gi * gg;
    h[r] = go * fast_tanh(cq[r]);
  }
}

// Stage full h (512 tagged words: {2 bf16 | tag}) into LDS hbuf; 2 words/thr.
__device__ __forceinline__ void stage_h(const u64* pubt, u32 tg, int tid,
                                        u16 hb[4][264]) {
  const u64* bp = pubt + (size_t)tid * 2;
  u64 v0 = aload(bp), v1 = aload(bp + 1);
  while ((u32)(v0 >> 32) != tg) v0 = aload(bp);
  while ((u32)(v1 >> 32) != tg) v1 = aload(bp + 1);
  const int w0 = tid * 2, w1 = w0 + 1;
  *(u32*)&hb[w0 >> 7][(w0 & 127) * 2] = (u32)v0;
  *(u32*)&hb[w1 >> 7][(w1 & 127) * 2] = (u32)v1;
}

// acc[m] += Wtile(m) @ h for this wave's dim-group; A-frags from LDS.
__device__ __forceinline__ void mfma8(const u16* ldsbase, const u16* hr, int l,
                                      int G, f32x4 (&acc)[4]) {
#pragma unroll
  for (int kk = 0; kk < 8; ++kk) {
    const short8 bk = *(const short8*)(hr + kk * 32 + G * 8);
#pragma unroll
    for (int m = 0; m < 4; ++m)
      acc[m] = MFMA16(*(const short8*)(ldsbase + (size_t)m * 4096 + kk * 512 + l * 8),
                      bk, acc[m]);
  }
}

// ---------------- prep: pack W_hh0/W_ih1/W_hh1 into bf16 MFMA-frag layout ----
// pk[mat][ti][kk][ll][j]: ti = dg*4 + m (dg 0..15, m 0..3);
// row = m*256 + dg*16 + (ll&15); k = kk*32 + (ll>>4)*8 + j.
__global__ __launch_bounds__(256) void prep_pack2(
    const float* __restrict__ whh0, const float* __restrict__ wih1,
    const float* __restrict__ whh1, const float* __restrict__ bi1,
    const float* __restrict__ bh1, u16* __restrict__ pk,
    float* __restrict__ bias1s) {
  const int idx = blockIdx.x * 256 + threadIdx.x;
  if (idx < 786432) {
    const int mat = idx >> 18;
    const int e = idx & 262143;
    const int ti = e >> 12, r2 = e & 4095;
    const int kk = r2 >> 9, ll = (r2 >> 3) & 63, j = r2 & 7;
    const int dg = ti >> 2, m = ti & 3;
    const int row = m * 256 + dg * 16 + (ll & 15);
    const int k = kk * 32 + (ll >> 4) * 8 + j;
    const float* src = (mat == 0) ? whh0 : (mat == 1) ? wih1 : whh1;
    pk[idx] = f2bf(src[(size_t)row * 256 + k]);
  } else {
    const int i = idx - 786432;
    if (i < 1024) bias1s[i] = bi1[i] + bh1[i];
  }
}

// --------------------- xw0 = x @ w_ih0^T + biases, packed bf16 ----------------
__global__ __launch_bounds__(256) void xw_gemm_bf(
    const float* __restrict__ xin, const float* __restrict__ w,
    const float* __restrict__ ba, const float* __restrict__ bb,
    u16* __restrict__ xwp) {
  __shared__ float xs[4][HD];
  const int blk = blockIdx.x, tid = threadIdx.x;
  const int row0 = blk * 4;
  for (int i = tid; i < 4 * HD; i += 256) xs[i >> 8][i & 255] = xin[(size_t)row0 * HD + i];
  __syncthreads();
  float acc[4][4];
#pragma unroll
  for (int g = 0; g < 4; ++g)
#pragma unroll
    for (int tt = 0; tt < 4; ++tt) acc[g][tt] = 0.f;
#pragma unroll 2
  for (int kc = 0; kc < 64; ++kc) {
#pragma unroll
    for (int g = 0; g < 4; ++g) {
      const int r = g * HD + tid;
      const float4 wv = ((const float4*)(w + (size_t)r * HD))[kc];
#pragma unroll
      for (int tt = 0; tt < 4; ++tt) {
        const float4 hv = ((const float4*)xs[tt])[kc];
        acc[g][tt] += wv.x * hv.x + wv.y * hv.y + wv.z * hv.z + wv.w * hv.w;
      }
    }
  }
#pragma unroll
  for (int g = 0; g < 4; ++g) {
    const int r = g * HD + tid;
    const float bias = ba[r] + bb[r];
#pragma unroll
    for (int tt = 0; tt < 4; ++tt)
      xwp[(size_t)(row0 + tt) * 1024 + r] = f2bf(acc[g][tt] + bias);
  }
}

// ------------------------------------------------------- 12-CU LSTM pipeline
__global__ __launch_bounds__(256) void lstm12(
    const u16* __restrict__ xwp, const u16* __restrict__ pk,
    const float* __restrict__ bias1s, float* __restrict__ hs1,
    u64* __restrict__ pubH0, u64* __restrict__ pubH1,
    u64* __restrict__ pubX1) {
  __shared__ __align__(16) u16 ldsW[16][4096];   // 128 KB: this CU's 16 tiles
  __shared__ __align__(16) u16 hbuf[2][4][264];  // h bf16, ping-pong

  const int role = blockIdx.x >> 2;  // 0: L0, 1: streamer, 2: L1
  const int j = blockIdx.x & 3;      // CU index within role
  const int tid = threadIdx.x;
  const int w = tid >> 6, l = tid & 63;
  const int r16 = l & 15, G = l >> 4;
  const bool active = (r16 < 4);
  const int b = r16;
  const int beff = active ? b : 3;
  const int dg = j * 4 + w;          // dim-group 0..15 (16 dims each)
  const int d0 = dg * 16 + G * 4;
  const u16* pkm = pk + (size_t)role * 262144;
  const u16* lw = &ldsW[w * 4][0];

  for (int i = tid; i < 2 * 4 * 264; i += 256) ((u16*)hbuf)[i] = 0;
  // fill LDS weight tiles: slot s = ws*4+m  <->  tile ti = (j*4+ws)*4+m
  for (int u = tid; u < 8192; u += 256) {
    const int s = u >> 9, inner = u & 511;
    const int ti = (j * 4 + (s >> 2)) * 4 + (s & 3);
    *(short8*)&ldsW[s][inner * 8] = *(const short8*)(pkm + (size_t)ti * 4096 + inner * 8);
  }
  __syncthreads();

  if (role == 0) {
    // ---------------- layer 0 ----------------
    f32x4 c = {0.f, 0.f, 0.f, 0.f};
    uint2 xn[4];
    if (active) {
#pragma unroll
      for (int m = 0; m < 4; ++m)
        xn[m] = *(const uint2*)(xwp + (size_t)b * SEQ * 1024 + m * 256 + d0);
    }
    for (int t = 0; t < SEQ; ++t) {
      const int cur = t & 1;
      if (t > 0) stage_h(pubH0 + (size_t)(t - 1) * 512, (u32)t, tid, hbuf[cur]);
      __syncthreads();
      f32x4 acc[4];
#pragma unroll
      for (int m = 0; m < 4; ++m) acc[m] = active ? unpack4(xn[m]) : f32x4{0.f, 0.f, 0.f, 0.f};
      if (active && t + 1 < SEQ) {
#pragma unroll
        for (int m = 0; m < 4; ++m)
          xn[m] = *(const uint2*)(xwp + ((size_t)b * SEQ + t + 1) * 1024 + m * 256 + d0);
      }
      mfma8(lw, &hbuf[cur][beff][0], l, G, acc);
      if (active) {
        f32x4 h;
        epi_h(acc, c, h);
        const u32 lo = pk2(h[0], h[1]), hi = pk2(h[2], h[3]);
        const u64 tg = (u64)(u32)(t + 1) << 32;
        const size_t wi = (size_t)t * 512 + b * 128 + dg * 8 + G * 2;
        astore(pubH0 + wi, (u64)lo | tg);
        astore(pubH0 + wi + 1, (u64)hi | tg);
      }
    }
  } else if (role == 1) {
    // ---------------- xw1 streamer ----------------
    f32x4 biasv[4];
#pragma unroll
    for (int m = 0; m < 4; ++m) biasv[m] = *(const f32x4*)(bias1s + m * 256 + d0);
    for (int t = 0; t < SEQ; ++t) {
      const int cur = t & 1;
      stage_h(pubH0 + (size_t)t * 512, (u32)(t + 1), tid, hbuf[cur]);
      __syncthreads();
      f32x4 acc[4];
#pragma unroll
      for (int m = 0; m < 4; ++m) acc[m] = biasv[m];
      mfma8(lw, &hbuf[cur][beff][0], l, G, acc);
      if (active) {
        const u64 tg = (u64)(u32)(t + 1) << 32;
        u64* xb = pubX1 + ((((size_t)t * 4 + j) * 4 + w) * 16 + (b * 4 + G)) * 16;
#pragma unroll
        for (int m = 0; m < 4; ++m)
#pragma unroll
          for (int r = 0; r < 4; ++r)
            astore(xb + m * 4 + r, (u64)__float_as_uint(acc[m][r]) | tg);
      }
    }
  } else {
    // ---------------- layer 1 ----------------
    f32x4 c = {0.f, 0.f, 0.f, 0.f};
    for (int t = 0; t < SEQ; ++t) {
      const int cur = t & 1;
      if (t > 0) stage_h(pubH1 + (size_t)(t - 1) * 512, (u32)t, tid, hbuf[cur]);
      __syncthreads();
      f32x4 acc[4];
      if (active) {
        const u64* xb = pubX1 + ((((size_t)t * 4 + j) * 4 + w) * 16 + (b * 4 + G)) * 16;
        u64 v[16];
        for (;;) {
#pragma unroll
          for (int s = 0; s < 16; ++s) v[s] = aload(xb + s);
          bool ok = true;
#pragma unroll
          for (int s = 0; s < 16; ++s) ok = ok && ((u32)(v[s] >> 32) == (u32)(t + 1));
          if (__all(ok)) break;
        }
#pragma unroll
        for (int m = 0; m < 4; ++m)
          acc[m] = f32x4{__uint_as_float((u32)v[m * 4 + 0]), __uint_as_float((u32)v[m * 4 + 1]),
                         __uint_as_float((u32)v[m * 4 + 2]), __uint_as_float((u32)v[m * 4 + 3])};
      } else {
#pragma unroll
        for (int m = 0; m < 4; ++m) acc[m] = f32x4{0.f, 0.f, 0.f, 0.f};
      }
      mfma8(lw, &hbuf[cur][beff][0], l, G, acc);
      if (active) {
        f32x4 h;
        epi_h(acc, c, h);
        const u32 lo = pk2(h[0], h[1]), hi = pk2(h[2], h[3]);
        const u64 tg = (u64)(u32)(t + 1) << 32;
        const size_t wi = (size_t)t * 512 + b * 128 + dg * 8 + G * 2;
        astore(pubH1 + wi, (u64)lo | tg);
        astore(pubH1 + wi + 1, (u64)hi | tg);
        *(float4*)(hs1 + ((size_t)b * SEQ + t) * HD + d0) =
            make_float4(h[0], h[1], h[2], h[3]);
      }
    }
  }
}

// ------------------------------------------------- head: stats = h @ w_lin^T + b
__global__ __launch_bounds__(256) void head_stats(
    const float* __restrict__ hs1, const float* __restrict__ wlin,
    const float* __restrict__ blin, float* __restrict__ mu_out,
    float* __restrict__ sd_out) {
  __shared__ float hsm[4][HD];
  const int blk = blockIdx.x, tid = threadIdx.x;
  const int row0 = blk * 4;
  for (int i = tid; i < 4 * HD; i += 256) hsm[i >> 8][i & 255] = hs1[(size_t)row0 * HD + i];
  __syncthreads();
  const float4* wsd = (const float4*)(wlin + (size_t)tid * HD);
  const float4* wmu = (const float4*)(wlin + (size_t)(HD + tid) * HD);
  float asd[4] = {0, 0, 0, 0}, amu[4] = {0, 0, 0, 0};
#pragma unroll 4
  for (int kc = 0; kc < 64; ++kc) {
    const float4 ws = wsd[kc], wm = wmu[kc];
#pragma unroll
    for (int tt = 0; tt < 4; ++tt) {
      const float4 hv = ((const float4*)hsm[tt])[kc];
      asd[tt] += ws.x * hv.x + ws.y * hv.y + ws.z * hv.z + ws.w * hv.w;
      amu[tt] += wm.x * hv.x + wm.y * hv.y + wm.z * hv.z + wm.w * hv.w;
    }
  }
  const float bsd = blin[tid], bmu = blin[HD + tid];
#pragma unroll
  for (int tt = 0; tt < 4; ++tt) {
    const float zs = asd[tt] + bsd;
    const float sp = (zs > 15.f) ? zs : __logf(1.f + __expf(zs));  // softplus
    sd_out[(size_t)(row0 + tt) * HD + tid] = sp;
    mu_out[(size_t)(row0 + tt) * HD + tid] = amu[tt] + bmu;
  }
}

// ---------------------------------- finalize: std_full + sample
__global__ __launch_bounds__(256) void finalize_fill(
    const float* __restrict__ eps, float* __restrict__ out) {
  float* sample = out;        // currently holds softplus(std) temp
  float* mu = out + 524288;
  float* sf = out + 1048576;  // [2048][256][256]
  const int row = blockIdx.x;
  const int tid = threadIdx.x;
  __shared__ float sd[HD];
  sd[tid] = sample[(size_t)row * HD + tid];
  __syncthreads();
  float4* dst = (float4*)(sf + (size_t)row * HD * HD);
  const int rr = tid >> 6, m = tid & 63;
#pragma unroll 4
  for (int g = 0; g < 64; ++g) {
    const int r = g * 4 + rr;
    float4 v = make_float4(0.f, 0.f, 0.f, 0.f);
    const int base = m * 4;
    if (r >= base && r < base + 4) ((float*)&v)[r - base] = sd[r];
    dst[(size_t)r * 64 + m] = v;
  }
  const float mu_v = mu[(size_t)row * HD + tid];
  const float e = eps[(size_t)row * HD + tid];
  sample[(size_t)row * HD + tid] = mu_v + sqrtf(sd[tid]) * e;
}

extern "C" void kernel_launch(void* const* d_in, const int* in_sizes, int n_in,
                              void* d_out, int out_size, void* d_ws, size_t ws_size,
                              hipStream_t stream) {
  const float* x     = (const float*)d_in[0];
  const float* eps   = (const float*)d_in[1];
  const float* w_ih0 = (const float*)d_in[2];
  const float* w_hh0 = (const float*)d_in[3];
  const float* b_ih0 = (const float*)d_in[4];
  const float* b_hh0 = (const float*)d_in[5];
  const float* w_ih1 = (const float*)d_in[6];
  const float* w_hh1 = (const float*)d_in[7];
  const float* b_ih1 = (const float*)d_in[8];
  const float* b_hh1 = (const float*)d_in[9];
  const float* w_lin = (const float*)d_in[10];
  const float* b_lin = (const float*)d_in[11];
  float* out = (float*)d_out;

  // Scratch carved from std_full output region (fully rewritten by finalize
  // each call -> tags never stale at launch; replay-safe).
  float* scratch = out + 1048576;
  u16*   xwp    = (u16*)scratch;                // 2,097,152 u16 (4 MB)
  float* hs1    = scratch + 1048576;            //   524,288 f32
  u16*   pkW    = (u16*)(scratch + 1572864);    //   786,432 u16
  float* bias1s = scratch + 1966080;            //     1,024 f32
  u64*   pubH0  = (u64*)(scratch + 1967104);    //   262,144 u64 (2 MB)
  u64*   pubH1  = (u64*)(scratch + 2491392);    //   262,144 u64 (2 MB)
  u64*   pubX1  = (u64*)(scratch + 3015680);    // 2,097,152 u64 (16 MB)

  hipLaunchKernelGGL(prep_pack2, dim3(3076), dim3(256), 0, stream,
                     w_hh0, w_ih1, w_hh1, b_ih1, b_hh1, pkW, bias1s);
  hipLaunchKernelGGL(xw_gemm_bf, dim3(512), dim3(256), 0, stream,
                     x, w_ih0, b_ih0, b_hh0, xwp);
  hipLaunchKernelGGL(lstm12, dim3(12), dim3(256), 0, stream,
                     xwp, pkW, bias1s, hs1, pubH0, pubH1, pubX1);
  hipLaunchKernelGGL(head_stats, dim3(512), dim3(256), 0, stream, hs1, w_lin, b_lin,
                     out + 524288, out);
  hipLaunchKernelGGL(finalize_fill, dim3(2048), dim3(256), 0, stream, eps, out);
}

// Round 12
// 2199.966 us; speedup vs baseline: 2.3682x; 1.1276x over previous
//
#include <hip/hip_runtime.h>
#include <hip/hip_bf16.h>

// GaussianLSTM: x(4,512,256) -> 2-layer LSTM(H=256) -> Gaussian head.
// Outputs concat: sample (524288) | mu (524288) | std_full (134217728) f32.
//
// Round 12: 12-CU two-role pipeline, counter sync, minimal agent stores.
//   r11 finding: each 8B agent atomic store costs ~32B HBM write (no
//   combining) -> 2.5M stores = the constant ~72MB WRITE_SIZE; pubX1 (16MB
//   payload, 64MB EA) + its 16-word tag polls were the pipeline bottleneck.
//   - L0: 4 CUs x 64 dims, W_hh0 slice 128KB LDS (r11 structure).
//   - L1: 8 CUs x 32 dims, W_ih1 + W_hh1 slices (64+64KB LDS) -> computes
//     xw1 locally; pubX1 + streamer role DELETED.
//   - Streams: h0/h1 only, 1 packed u64 (4 bf16) per active lane per step.
//   - Sync: per-step counters. Producer: data astores -> vmcnt(0) ->
//     atomicAdd(cnt[t]). Consumer: lane0 polls one word to target ->
//     barrier -> parallel 8B aloads (payloads need no tags).
//   - Replay-safe: counters zeroed by prep_pack each call (kernel-boundary
//     coherence); pubs read only after this-call counters reach target.

#define HD 256
#define SEQ 512

typedef __attribute__((ext_vector_type(8))) short short8;
typedef __attribute__((ext_vector_type(4))) float f32x4;
using u16 = unsigned short;
using u32 = unsigned int;
using u64 = unsigned long long;

#define MFMA16(a, bm, c) __builtin_amdgcn_mfma_f32_16x16x32_bf16((a), (bm), (c), 0, 0, 0)

__device__ inline u16 f2bf(float x) {
  u32 u = __float_as_uint(x);
  u32 r = (u + 0x7FFFu + ((u >> 16) & 1u)) >> 16;
  return (u16)r;
}
__device__ inline u64 pk4(float a, float b, float c, float d) {
  return (u64)f2bf(a) | ((u64)f2bf(b) << 16) | ((u64)f2bf(c) << 32) |
         ((u64)f2bf(d) << 48);
}
__device__ inline float fast_sigmoid(float z) { return 1.0f / (1.0f + __expf(-z)); }
__device__ inline float fast_tanh(float z) { return 1.0f - 2.0f / (1.0f + __expf(2.0f * z)); }

__device__ __forceinline__ u64 aload(const u64* p) {
  return __hip_atomic_load(p, __ATOMIC_RELAXED, __HIP_MEMORY_SCOPE_AGENT);
}
__device__ __forceinline__ void astore(u64* p, u64 v) {
  __hip_atomic_store(p, v, __ATOMIC_RELAXED, __HIP_MEMORY_SCOPE_AGENT);
}
__device__ __forceinline__ u32 aload32(const u32* p) {
  return __hip_atomic_load(p, __ATOMIC_RELAXED, __HIP_MEMORY_SCOPE_AGENT);
}
__device__ __forceinline__ void aadd32(u32* p) {
  __hip_atomic_fetch_add(p, 1u, __ATOMIC_RELAXED, __HIP_MEMORY_SCOPE_AGENT);
}

__device__ __forceinline__ f32x4 unpack4(uint2 p) {
  return f32x4{__uint_as_float(p.x << 16), __uint_as_float(p.x & 0xFFFF0000u),
               __uint_as_float(p.y << 16), __uint_as_float(p.y & 0xFFFF0000u)};
}

__device__ __forceinline__ void epi_h(const f32x4 (&acc)[4], f32x4& cq, f32x4& h) {
#pragma unroll
  for (int r = 0; r < 4; ++r) {
    const float gi = fast_sigmoid(acc[0][r]);
    const float gf = fast_sigmoid(acc[1][r]);
    const float gg = fast_tanh(acc[2][r]);
    const float go = fast_sigmoid(acc[3][r]);
    cq[r] = gf * cq[r] + gi * gg;
    h[r] = go * fast_tanh(cq[r]);
  }
}

// acc[m] += Wtile(m) @ h; A-fragments from LDS (4 gate tiles at ldsbase).
__device__ __forceinline__ void mfma8(const u16* ldsbase, const u16* hr, int l,
                                      int G, f32x4 (&acc)[4]) {
#pragma unroll
  for (int kk = 0; kk < 8; ++kk) {
    const short8 bk = *(const short8*)(hr + kk * 32 + G * 8);
#pragma unroll
    for (int m = 0; m < 4; ++m)
      acc[m] = MFMA16(*(const short8*)(ldsbase + (size_t)m * 4096 + kk * 512 + l * 8),
                      bk, acc[m]);
  }
}

// ---------------- prep: pack weights to MFMA-frag layout + zero counters ----
// pk[mat][ti][kk][ll][j]: ti = dg*4+m; row = m*256+dg*16+(ll&15);
// k = kk*32+(ll>>4)*8+j.
__global__ __launch_bounds__(256) void prep_pack3(
    const float* __restrict__ whh0, const float* __restrict__ wih1,
    const float* __restrict__ whh1, const float* __restrict__ bi1,
    const float* __restrict__ bh1, u16* __restrict__ pk,
    float* __restrict__ bias1s, u32* __restrict__ cnt) {
  const int idx = blockIdx.x * 256 + threadIdx.x;
  if (idx < 786432) {
    const int mat = idx >> 18;
    const int e = idx & 262143;
    const int ti = e >> 12, r2 = e & 4095;
    const int kk = r2 >> 9, ll = (r2 >> 3) & 63, j = r2 & 7;
    const int dg = ti >> 2, m = ti & 3;
    const int row = m * 256 + dg * 16 + (ll & 15);
    const int k = kk * 32 + (ll >> 4) * 8 + j;
    const float* src = (mat == 0) ? whh0 : (mat == 1) ? wih1 : whh1;
    pk[idx] = f2bf(src[(size_t)row * 256 + k]);
  } else if (idx < 787456) {
    const int i = idx - 786432;
    bias1s[i] = bi1[i] + bh1[i];
  } else if (idx < 788480) {
    cnt[idx - 787456] = 0;  // cnt0[512] | cnt1[512]
  }
}

// --------------------- xw0 = x @ w_ih0^T + biases, packed bf16 ----------------
__global__ __launch_bounds__(256) void xw_gemm_bf(
    const float* __restrict__ xin, const float* __restrict__ w,
    const float* __restrict__ ba, const float* __restrict__ bb,
    u16* __restrict__ xwp) {
  __shared__ float xs[4][HD];
  const int blk = blockIdx.x, tid = threadIdx.x;
  const int row0 = blk * 4;
  for (int i = tid; i < 4 * HD; i += 256) xs[i >> 8][i & 255] = xin[(size_t)row0 * HD + i];
  __syncthreads();
  float acc[4][4];
#pragma unroll
  for (int g = 0; g < 4; ++g)
#pragma unroll
    for (int tt = 0; tt < 4; ++tt) acc[g][tt] = 0.f;
#pragma unroll 2
  for (int kc = 0; kc < 64; ++kc) {
#pragma unroll
    for (int g = 0; g < 4; ++g) {
      const int r = g * HD + tid;
      const float4 wv = ((const float4*)(w + (size_t)r * HD))[kc];
#pragma unroll
      for (int tt = 0; tt < 4; ++tt) {
        const float4 hv = ((const float4*)xs[tt])[kc];
        acc[g][tt] += wv.x * hv.x + wv.y * hv.y + wv.z * hv.z + wv.w * hv.w;
      }
    }
  }
#pragma unroll
  for (int g = 0; g < 4; ++g) {
    const int r = g * HD + tid;
    const float bias = ba[r] + bb[r];
#pragma unroll
    for (int tt = 0; tt < 4; ++tt)
      xwp[(size_t)(row0 + tt) * 1024 + r] = f2bf(acc[g][tt] + bias);
  }
}

// ------------------------------------------------------- 12-CU LSTM pipeline
__global__ __launch_bounds__(256) void lstm2r(
    const u16* __restrict__ xwp, const u16* __restrict__ pk,
    const float* __restrict__ bias1s, float* __restrict__ hs1,
    u64* __restrict__ pubH0, u64* __restrict__ pubH1,
    u32* __restrict__ cnt0, u32* __restrict__ cnt1) {
  __shared__ __align__(16) u16 ldsW[16][4096];  // 128 KB weight tiles
  __shared__ __align__(16) u16 h0buf[4][272];
  __shared__ __align__(16) u16 h1buf[4][272];
  __shared__ float pacc[2][16][16];             // L1 partial accs

  const int bid = blockIdx.x;
  const int role = (bid < 4) ? 0 : 1;
  const int j = (role == 0) ? bid : bid - 4;
  const int tid = threadIdx.x;
  const int w = tid >> 6, l = tid & 63;
  const int r16 = l & 15, G = l >> 4;
  const bool active = (r16 < 4);
  const int b = r16;
  const int beff = active ? b : 3;

  // zero h bufs
  for (int i = tid; i < 4 * 272; i += 256) { h0buf[i / 272][i % 272] = 0; h1buf[i / 272][i % 272] = 0; }
  // fill LDS weight tiles
  for (int u = tid; u < 8192; u += 256) {
    const int s = u >> 9, inner = u & 511;
    size_t ti;
    if (role == 0) {
      ti = (size_t)((j * 4 + (s >> 2)) * 4 + (s & 3));               // W_hh0
    } else if (s < 8) {
      ti = 65536 / 4096 * 16 + 0;  // placeholder (overwritten below)
      ti = (size_t)262144 / 4096;  // unused
    }
    if (role == 0) {
      *(short8*)&ldsW[s][inner * 8] = *(const short8*)(pk + ti * 4096 + inner * 8);
    } else {
      const int s2 = (s < 8) ? s : s - 8;
      const size_t base = (s < 8) ? 262144 : 524288;                 // W_ih1 / W_hh1
      const size_t t2 = (size_t)((j * 2 + (s2 >> 2)) * 4 + (s2 & 3));
      *(short8*)&ldsW[s][inner * 8] = *(const short8*)(pk + base + t2 * 4096 + inner * 8);
    }
  }
  __syncthreads();

  if (role == 0) {
    // ---------------- layer 0: owns dims [j*64, j*64+64) ----------------
    const int dg = j * 4 + w;
    const int d0 = dg * 16 + G * 4;
    const u16* lw = &ldsW[w * 4][0];
    f32x4 c = {0.f, 0.f, 0.f, 0.f};
    uint2 xn[4];
    if (active) {
#pragma unroll
      for (int m = 0; m < 4; ++m)
        xn[m] = *(const uint2*)(xwp + (size_t)b * SEQ * 1024 + m * 256 + d0);
    }
    for (int t = 0; t < SEQ; ++t) {
      if (t > 0) {
        if (tid == 0) while (aload32(cnt0 + t - 1) < 4u) {}
        __syncthreads();
        const u64 v = aload(pubH0 + (size_t)(t - 1) * 256 + tid);
        *(u64*)&h0buf[(tid >> 2) & 3][(tid >> 4) * 16 + (tid & 3) * 4] = v;
      }
      __syncthreads();
      f32x4 acc[4];
#pragma unroll
      for (int m = 0; m < 4; ++m) acc[m] = active ? unpack4(xn[m]) : f32x4{0.f, 0.f, 0.f, 0.f};
      mfma8(lw, &h0buf[beff][0], l, G, acc);
      if (active) {
        f32x4 h;
        epi_h(acc, c, h);
        astore(pubH0 + (size_t)t * 256 + (dg * 16 + b * 4 + G), pk4(h[0], h[1], h[2], h[3]));
      }
      asm volatile("s_waitcnt vmcnt(0)" ::: "memory");
      if (active && t + 1 < SEQ) {
#pragma unroll
        for (int m = 0; m < 4; ++m)
          xn[m] = *(const uint2*)(xwp + ((size_t)b * SEQ + t + 1) * 1024 + m * 256 + d0);
      }
      __syncthreads();
      if (tid == 0) aadd32(cnt0 + t);
    }
  } else {
    // ---------------- layer 1: owns dims [j*32, j*32+32) ----------------
    const int dgl = w >> 1;        // local dim-group 0..1
    const int mat = w & 1;         // 0 = W_ih1 (h0), 1 = W_hh1 (h1)
    const int dg1 = j * 2 + dgl;
    const int d0 = dg1 * 16 + G * 4;
    const u16* lw = &ldsW[mat * 8 + dgl * 4][0];
    f32x4 biasv[4];
#pragma unroll
    for (int m = 0; m < 4; ++m) biasv[m] = *(const f32x4*)(bias1s + m * 256 + d0);
    f32x4 c = {0.f, 0.f, 0.f, 0.f};

    for (int t = 0; t < SEQ; ++t) {
      if (tid == 0) {
        if (t > 0) while (aload32(cnt1 + t - 1) < 8u) {}
        while (aload32(cnt0 + t) < 4u) {}
      }
      __syncthreads();
      {  // stage h0(t) and h1(t-1): 1 word each per thread
        const u64 v0 = aload(pubH0 + (size_t)t * 256 + tid);
        u64 v1 = 0;
        if (t > 0) v1 = aload(pubH1 + (size_t)(t - 1) * 256 + tid);
        const int sb = (tid >> 2) & 3, sd = (tid >> 4) * 16 + (tid & 3) * 4;
        *(u64*)&h0buf[sb][sd] = v0;
        if (t > 0) *(u64*)&h1buf[sb][sd] = v1;
      }
      __syncthreads();
      f32x4 acc[4];
#pragma unroll
      for (int m = 0; m < 4; ++m)
        acc[m] = (mat == 0) ? biasv[m] : f32x4{0.f, 0.f, 0.f, 0.f};
      const u16* hr = (mat == 0) ? &h0buf[beff][0] : &h1buf[beff][0];
      mfma8(lw, hr, l, G, acc);
      if (mat == 1 && active) {
#pragma unroll
        for (int m = 0; m < 4; ++m)
#pragma unroll
          for (int r = 0; r < 4; ++r) pacc[dgl][b * 4 + G][m * 4 + r] = acc[m][r];
      }
      __syncthreads();
      if (mat == 0 && active) {
#pragma unroll
        for (int m = 0; m < 4; ++m)
#pragma unroll
          for (int r = 0; r < 4; ++r) acc[m][r] += pacc[dgl][b * 4 + G][m * 4 + r];
        f32x4 h;
        epi_h(acc, c, h);
        *(f32x4*)(hs1 + ((size_t)b * SEQ + t) * HD + d0) = h;
        astore(pubH1 + (size_t)t * 256 + (dg1 * 16 + b * 4 + G), pk4(h[0], h[1], h[2], h[3]));
      }
      asm volatile("s_waitcnt vmcnt(0)" ::: "memory");
      __syncthreads();
      if (tid == 0) aadd32(cnt1 + t);
    }
  }
}

// ------------------------------------------------- head: stats = h @ w_lin^T + b
__global__ __launch_bounds__(256) void head_stats(
    const float* __restrict__ hs1, const float* __restrict__ wlin,
    const float* __restrict__ blin, float* __restrict__ mu_out,
    float* __restrict__ sd_out) {
  __shared__ float hsm[4][HD];
  const int blk = blockIdx.x, tid = threadIdx.x;
  const int row0 = blk * 4;
  for (int i = tid; i < 4 * HD; i += 256) hsm[i >> 8][i & 255] = hs1[(size_t)row0 * HD + i];
  __syncthreads();
  const float4* wsd = (const float4*)(wlin + (size_t)tid * HD);
  const float4* wmu = (const float4*)(wlin + (size_t)(HD + tid) * HD);
  float asd[4] = {0, 0, 0, 0}, amu[4] = {0, 0, 0, 0};
#pragma unroll 4
  for (int kc = 0; kc < 64; ++kc) {
    const float4 ws = wsd[kc], wm = wmu[kc];
#pragma unroll
    for (int tt = 0; tt < 4; ++tt) {
      const float4 hv = ((const float4*)hsm[tt])[kc];
      asd[tt] += ws.x * hv.x + ws.y * hv.y + ws.z * hv.z + ws.w * hv.w;
      amu[tt] += wm.x * hv.x + wm.y * hv.y + wm.z * hv.z + wm.w * hv.w;
    }
  }
  const float bsd = blin[tid], bmu = blin[HD + tid];
#pragma unroll
  for (int tt = 0; tt < 4; ++tt) {
    const float zs = asd[tt] + bsd;
    const float sp = (zs > 15.f) ? zs : __logf(1.f + __expf(zs));  // softplus
    sd_out[(size_t)(row0 + tt) * HD + tid] = sp;
    mu_out[(size_t)(row0 + tt) * HD + tid] = amu[tt] + bmu;
  }
}

// ---------------------------------- finalize: std_full + sample
__global__ __launch_bounds__(256) void finalize_fill(
    const float* __restrict__ eps, float* __restrict__ out) {
  float* sample = out;        // currently holds softplus(std) temp
  float* mu = out + 524288;
  float* sf = out + 1048576;  // [2048][256][256]
  const int row = blockIdx.x;
  const int tid = threadIdx.x;
  __shared__ float sd[HD];
  sd[tid] = sample[(size_t)row * HD + tid];
  __syncthreads();
  float4* dst = (float4*)(sf + (size_t)row * HD * HD);
  const int rr = tid >> 6, m = tid & 63;
#pragma unroll 4
  for (int g = 0; g < 64; ++g) {
    const int r = g * 4 + rr;
    float4 v = make_float4(0.f, 0.f, 0.f, 0.f);
    const int base = m * 4;
    if (r >= base && r < base + 4) ((float*)&v)[r - base] = sd[r];
    dst[(size_t)r * 64 + m] = v;
  }
  const float mu_v = mu[(size_t)row * HD + tid];
  const float e = eps[(size_t)row * HD + tid];
  sample[(size_t)row * HD + tid] = mu_v + sqrtf(sd[tid]) * e;
}

extern "C" void kernel_launch(void* const* d_in, const int* in_sizes, int n_in,
                              void* d_out, int out_size, void* d_ws, size_t ws_size,
                              hipStream_t stream) {
  const float* x     = (const float*)d_in[0];
  const float* eps   = (const float*)d_in[1];
  const float* w_ih0 = (const float*)d_in[2];
  const float* w_hh0 = (const float*)d_in[3];
  const float* b_ih0 = (const float*)d_in[4];
  const float* b_hh0 = (const float*)d_in[5];
  const float* w_ih1 = (const float*)d_in[6];
  const float* w_hh1 = (const float*)d_in[7];
  const float* b_ih1 = (const float*)d_in[8];
  const float* b_hh1 = (const float*)d_in[9];
  const float* w_lin = (const float*)d_in[10];
  const float* b_lin = (const float*)d_in[11];
  float* out = (float*)d_out;

  // Scratch carved from std_full output region (fully rewritten by finalize
  // each call; counters zeroed by prep each call -> replay-safe).
  float* scratch = out + 1048576;
  u16*   xwp    = (u16*)scratch;                // 2,097,152 u16 (4 MB)
  float* hs1    = scratch + 1048576;            //   524,288 f32
  u16*   pkW    = (u16*)(scratch + 1572864);    //   786,432 u16
  float* bias1s = scratch + 1966080;            //     1,024 f32
  u32*   cnt    = (u32*)(scratch + 1967104);    //     1,024 u32
  u64*   pubH0  = (u64*)(scratch + 1968128);    //   131,072 u64 (1 MB)
  u64*   pubH1  = (u64*)(scratch + 2230272);    //   131,072 u64 (1 MB)

  hipLaunchKernelGGL(prep_pack3, dim3(3080), dim3(256), 0, stream,
                     w_hh0, w_ih1, w_hh1, b_ih1, b_hh1, pkW, bias1s, cnt);
  hipLaunchKernelGGL(xw_gemm_bf, dim3(512), dim3(256), 0, stream,
                     x, w_ih0, b_ih0, b_hh0, xwp);
  hipLaunchKernelGGL(lstm2r, dim3(12), dim3(256), 0, stream,
                     xwp, pkW, bias1s, hs1, pubH0, pubH1, cnt, cnt + 512);
  hipLaunchKernelGGL(head_stats, dim3(512), dim3(256), 0, stream, hs1, w_lin, b_lin,
                     out + 524288, out);
  hipLaunchKernelGGL(finalize_fill, dim3(2048), dim3(256), 0, stream, eps, out);
}